// Round 13
// baseline (1003.275 us; speedup 1.0000x reference)
//
#include <hip/hip_runtime.h>
#include <math.h>

#define NROWS 131072
#define HID 256
#define NPAR 800
#define MROWS 64
#define NTHREADS 1024
#define NBLOCKS (NROWS / MROWS)      // 2048

#define W2F_FRAGS 25600              // 50 col-tiles * 8 k-steps * 64 lanes
#define W1F_BASE  51200              // s16x8 units: after W2F hi/lo pairs
#define LDS_HLO 32768
#define LDS_X   65536
#define LDS_PLD 804                  // 4*804 mod 32 banks = 16 -> quarter-groups 2-way (free)
#define LDS_TOTAL 73728              // 72 KB: hhi+hlo+x_c -> 2 blocks/CU; p_lds[16][804] overlays

typedef __attribute__((ext_vector_type(8))) short s16x8;
typedef __attribute__((ext_vector_type(4))) float f32x4;

__device__ __forceinline__ unsigned short bf16_rne(float f) {
    unsigned u = __float_as_uint(f);
    u += 0x7fffu + ((u >> 16) & 1u);
    return (unsigned short)(u >> 16);
}
__device__ __forceinline__ float bf16_to_f(unsigned short h) {
    return __uint_as_float((unsigned)h << 16);
}

// Pre-split W2 (fp32 [256][800]) and W1 (fp32 [32][256]) into bf16 hi/lo fragment
// pairs in per-lane MFMA B-operand order (hi/lo PAIRED, 32B contiguous per lane):
//   W2: pair g = ct*8+k0; lane l: 8 bf16 = W2[k0*32+(l>>4)*8+j][ct*16+(l&15)]
//   W1: ct in [0,16); lane l: 8 bf16 = W1[(l>>4)*8+j][ct*16+(l&15)]
__global__ void prep_w(const float* __restrict__ W2, const float* __restrict__ W1,
                       short* __restrict__ wsp)
{
    const int t = blockIdx.x * 256 + threadIdx.x;
    if (t < W2F_FRAGS) {
        const int l = t & 63;
        const int g = t >> 6;
        const int ct = g >> 3, k0 = g & 7;
        const int c  = (ct << 4) + (l & 15);
        const int kb = (k0 << 5) + ((l >> 4) << 3);
        s16x8 hi, lo;
#pragma unroll
        for (int j = 0; j < 8; ++j) {
            float v = W2[(size_t)(kb + j) * NPAR + c];
            unsigned short h = bf16_rne(v);
            unsigned short lw = bf16_rne(v - bf16_to_f(h));
            hi[j] = (short)h;
            lo[j] = (short)lw;
        }
        ((s16x8*)wsp)[g * 128 + l * 2]     = hi;
        ((s16x8*)wsp)[g * 128 + l * 2 + 1] = lo;
    } else if (t < W2F_FRAGS + 1024) {
        const int t1 = t - W2F_FRAGS;
        const int l  = t1 & 63;
        const int ct = t1 >> 6;                 // 0..15
        const int c  = (ct << 4) + (l & 15);
        const int kb = (l >> 4) << 3;
        s16x8 hi, lo;
#pragma unroll
        for (int j = 0; j < 8; ++j) {
            float v = W1[(size_t)(kb + j) * HID + c];
            unsigned short h = bf16_rne(v);
            unsigned short lw = bf16_rne(v - bf16_to_f(h));
            hi[j] = (short)h;
            lo[j] = (short)lw;
        }
        ((s16x8*)wsp)[W1F_BASE + ct * 128 + l * 2]     = hi;
        ((s16x8*)wsp)[W1F_BASE + ct * 128 + l * 2 + 1] = lo;
    }
}

__global__ __launch_bounds__(NTHREADS, 8)
void rqs_fused(const float* __restrict__ inp,
               const float* __restrict__ b1,
               const short* __restrict__ W2F,
               const float* __restrict__ b2,
               float* __restrict__ out)
{
    extern __shared__ char smem[];
    char*  hhi   = smem;                       // [64][256] bf16, XOR-swizzled (32 KB)
    char*  hlo   = smem + LDS_HLO;             // [64][256] bf16, XOR-swizzled (32 KB)
    char*  x_c   = smem + LDS_X;               // [64][32] fp32 x_id, XOR-swizzled (8 KB)
    float* p_lds = (float*)smem;               // [16][804] fp32, overlays (h dead by then)

    const int t    = threadIdx.x;
    const int row0 = blockIdx.x * MROWS;
    const int lane = t & 63;
    const int w    = t >> 6;                   // wave id 0..15
    const int arow = lane & 15;
    const int kgrp = lane >> 4;
    const int lane2 = lane << 1;

    const s16x8* BF = (const s16x8*)W2F;

    // wave w owns ct = w + 16*ci; waves 0,1 have 4 tiles (ct up to 49), rest 3.
    const int nct = (w < 2) ? 4 : 3;

    // ---- identity pass-through + x_id -> LDS (swizzled): 64 rows x 8 float4 ----
    if (t < 512) {
        const int r = t >> 3, q = t & 7;
        const float4 v = ((const float4*)(inp + (size_t)(row0 + r) * 64))[q];
        ((float4*)(out + (size_t)(row0 + r) * 64))[q] = v;
        int byte = (r << 7) + (q << 4);
        byte ^= (r & 7) << 4;                                    // bank swizzle
        *(float4*)(x_c + byte) = v;
    }
    __syncthreads();

    // ---- GEMM1 via MFMA: h = relu(x_id @ W1 + b1), 3-term bf16 split ----
    // wave w: row-half (w>>3), col-pair (w&7) -> 2 col-tiles x 2 row-tiles.
    {
        const int rh = w >> 3;                  // row half 0/1 (wave-uniform)
        const int wc = w & 7;                   // col pair 0..7

        s16x8 w1h[2], w1l[2];
#pragma unroll
        for (int cc = 0; cc < 2; ++cc) {
            const int f = (2 * wc + cc) * 128 + W1F_BASE + lane2;
            w1h[cc] = BF[f];
            w1l[cc] = BF[f + 1];
        }

        s16x8 xhi[2], xlo[2];
#pragma unroll
        for (int rt = 0; rt < 2; ++rt) {
            const int row  = rh * 32 + rt * 16 + arow;
            const int base = (row << 7) + (kgrp << 5);
            const int sw   = (row & 7) << 4;
            const float4 va = *(const float4*)(x_c + (base ^ sw));
            const float4 vb = *(const float4*)(x_c + ((base + 16) ^ sw));
            const float xv[8] = {va.x, va.y, va.z, va.w, vb.x, vb.y, vb.z, vb.w};
#pragma unroll
            for (int j = 0; j < 8; ++j) {
                unsigned short h = bf16_rne(xv[j]);
                xhi[rt][j] = (short)h;
                xlo[rt][j] = (short)bf16_rne(xv[j] - bf16_to_f(h));
            }
        }

        f32x4 g[2][2];
#pragma unroll
        for (int cc = 0; cc < 2; ++cc) {
            const float bias = b1[(2 * wc + cc) * 16 + arow];
            g[0][cc] = (f32x4){bias, bias, bias, bias};
            g[1][cc] = (f32x4){bias, bias, bias, bias};
        }

#pragma unroll
        for (int rt = 0; rt < 2; ++rt) {
#pragma unroll
            for (int cc = 0; cc < 2; ++cc) {
                g[rt][cc] = __builtin_amdgcn_mfma_f32_16x16x32_bf16(xhi[rt], w1h[cc], g[rt][cc], 0, 0, 0);
                g[rt][cc] = __builtin_amdgcn_mfma_f32_16x16x32_bf16(xhi[rt], w1l[cc], g[rt][cc], 0, 0, 0);
                g[rt][cc] = __builtin_amdgcn_mfma_f32_16x16x32_bf16(xlo[rt], w1h[cc], g[rt][cc], 0, 0, 0);
            }
        }

        // relu + bf16 hi/lo split + write to hhi/hlo (same layout GEMM2 reads)
#pragma unroll
        for (int rt = 0; rt < 2; ++rt) {
#pragma unroll
            for (int cc = 0; cc < 2; ++cc) {
                const int col = (2 * wc + cc) * 16 + arow;
#pragma unroll
                for (int i = 0; i < 4; ++i) {
                    const int row = rh * 32 + rt * 16 + (kgrp << 2) + i;
                    const float s = fmaxf(g[rt][cc][i], 0.0f);
                    unsigned short hs = bf16_rne(s);
                    unsigned short ls = bf16_rne(s - bf16_to_f(hs));
                    int byte = (row << 9) + (col << 1);
                    byte ^= (row & 7) << 4;
                    *(short*)(hhi + byte) = (short)hs;
                    *(short*)(hlo + byte) = (short)ls;
                }
            }
        }
    }
    __syncthreads();

    // ---- epilogue x prefetch: 4 phases x 16 rows, only t<512 participates ----
    float x_ep[4];
    if (t < 512) {
#pragma unroll
        for (int ph = 0; ph < 4; ++ph)
            x_ep[ph] = inp[(size_t)(row0 + ph * 16 + (t >> 5)) * 64 + 32 + (t & 31)];
    }

    // ---- GEMM2: 3-term bf16 split (hi*hi + hi*lo + lo*hi), acc[4][4] ----
    f32x4 acc[4][4];
#pragma unroll
    for (int ci = 0; ci < 4; ++ci)
#pragma unroll
        for (int rt = 0; rt < 4; ++rt)
            acc[ci][rt] = (f32x4){0.f, 0.f, 0.f, 0.f};

#pragma unroll 1
    for (int k0 = 0; k0 < 8; ++k0) {
        s16x8 ahi[4], alo[4];
#pragma unroll
        for (int rt = 0; rt < 4; ++rt) {
            const int row = rt * 16 + arow;
            int byte = (row << 9) + (k0 << 6) + (kgrp << 4);
            byte ^= (row & 7) << 4;
            ahi[rt] = *(const s16x8*)(hhi + byte);
            alo[rt] = *(const s16x8*)(hlo + byte);
        }
#pragma unroll
        for (int ci = 0; ci < 4; ++ci) {
            if (ci < nct) {
                const int ct = w + (ci << 4);                    // max 49
                const int f  = (ct * 8 + k0) * 128 + lane2;
                const s16x8 bh = BF[f];
                const s16x8 bl = BF[f + 1];
                __builtin_amdgcn_s_setprio(1);
#pragma unroll
                for (int rt = 0; rt < 4; ++rt) {
                    acc[ci][rt] = __builtin_amdgcn_mfma_f32_16x16x32_bf16(ahi[rt], bh, acc[ci][rt], 0, 0, 0);
                    acc[ci][rt] = __builtin_amdgcn_mfma_f32_16x16x32_bf16(ahi[rt], bl, acc[ci][rt], 0, 0, 0);
                    acc[ci][rt] = __builtin_amdgcn_mfma_f32_16x16x32_bf16(alo[rt], bh, acc[ci][rt], 0, 0, 0);
                }
                __builtin_amdgcn_s_setprio(0);
            }
        }
    }

    // ---- epilogue: 4 phases (16-row panels); stage 16 x 800, then 512 units ----
#pragma unroll
    for (int ph = 0; ph < 4; ++ph) {
        __syncthreads();                                        // p_lds safe to (re)write
#pragma unroll
        for (int ci = 0; ci < 4; ++ci) {
            if (ci < nct) {
                const int ct = w + (ci << 4);
                const float bias = b2[(ct << 4) + arow];
                const int col = (ct << 4) + arow;               // 0..799
                const f32x4 v = acc[ci][ph];                    // rows ph*16 .. ph*16+15
                const int rowl = kgrp << 2;                     // 0..12 (+reg)
                p_lds[(rowl + 0) * LDS_PLD + col] = v[0] + bias;
                p_lds[(rowl + 1) * LDS_PLD + col] = v[1] + bias;
                p_lds[(rowl + 2) * LDS_PLD + col] = v[2] + bias;
                p_lds[(rowl + 3) * LDS_PLD + col] = v[3] + bias;
            }
        }
        __syncthreads();

        // one (row, d) per active thread: 16 rows x 32 d = 512 units
        if (t < 512) {
            const int r_l = t >> 5;
            const int dl  = t & 31;
            const float* p = &p_lds[r_l * LDS_PLD + dl * 25];
            float pv[25];
#pragma unroll
            for (int j = 0; j < 25; ++j) pv[j] = p[j];

            float cw[9], ch[9];
            {
                float mw = pv[0];
#pragma unroll
                for (int j = 1; j < 8; ++j) mw = fmaxf(mw, pv[j]);
                float e[8], sw = 0.f;
#pragma unroll
                for (int j = 0; j < 8; ++j) { e[j] = __expf(pv[j] - mw); sw += e[j]; }
                const float scale = 0.992f / sw;
                float run = 0.f;
                cw[0] = 0.f;
#pragma unroll
                for (int j = 0; j < 8; ++j) { run += 0.001f + e[j] * scale; cw[j + 1] = run; }
                const float icn = 1.0f / fmaxf(cw[8], 1e-12f);
#pragma unroll
                for (int j = 1; j <= 8; ++j) cw[j] *= icn;
            }
            {
                float mh = pv[8];
#pragma unroll
                for (int j = 1; j < 8; ++j) mh = fmaxf(mh, pv[8 + j]);
                float e[8], sh = 0.f;
#pragma unroll
                for (int j = 0; j < 8; ++j) { e[j] = __expf(pv[8 + j] - mh); sh += e[j]; }
                const float scale = 0.992f / sh;
                float run = 0.f;
                ch[0] = 0.f;
#pragma unroll
                for (int j = 0; j < 8; ++j) { run += 0.001f + e[j] * scale; ch[j + 1] = run; }
                const float icn = 1.0f / fmaxf(ch[8], 1e-12f);
#pragma unroll
                for (int j = 1; j <= 8; ++j) ch[j] *= icn;
            }

            const int grow = row0 + ph * 16 + r_l;
            const float x = x_ep[ph];
            const float xs = fminf(fmaxf((x + 10.0f) * 0.05f, 0.f), 1.f);
            int b = 0;
#pragma unroll
            for (int j = 1; j <= 8; ++j) b += (xs >= cw[j]) ? 1 : 0;
            b = min(b, 7);

            float xk = 0.f, wk = 0.f, yk = 0.f, hk = 0.f;
#pragma unroll
            for (int j = 0; j < 8; ++j) {
                if (b == j) {
                    xk = cw[j]; wk = cw[j + 1] - cw[j];
                    yk = ch[j]; hk = ch[j + 1] - ch[j];
                }
            }
            // softplus only on the selected pair d[b], d[b+1]
            float ud0 = pv[16], ud1 = pv[17];
#pragma unroll
            for (int j = 1; j < 8; ++j) {
                const bool ge = (b >= j);
                ud0 = ge ? pv[16 + j] : ud0;
                ud1 = ge ? pv[17 + j] : ud1;
            }
            const float dk  = 0.001f + fmaxf(ud0, 0.f) + __logf(1.0f + __expf(-fabsf(ud0)));
            const float dk1 = 0.001f + fmaxf(ud1, 0.f) + __logf(1.0f + __expf(-fabsf(ud1)));

            const float EPSf = 1e-12f;
            const float tt = fminf(fmaxf((xs - xk) / (wk + EPSf), 0.f), 1.f);
            const float a = (hk + EPSf) / (wk + EPSf);
            const float omt = 1.f - tt;
            const float tomt = tt * omt;
            const float num = a * tt * tt + dk * tomt;
            const float den = a + (dk + dk1 - 2.f * a) * tomt;
            const float sres = num / (den + EPSf);
            const float ys = yk + hk * sres;
            float y = ys * 20.0f - 10.0f;
            const float dnum = a * a * (dk1 * tt * tt + 2.f * a * tomt + dk * omt * omt);
            const float dydx = dnum / (den * den + EPSf);
            float lad = __logf(fmaxf(dydx, 1e-12f));

            const bool inside = (x >= -10.0f) && (x <= 10.0f);
            if (!inside) { y = x; lad = 0.0f; }

            out[(size_t)grow * 64 + 32 + dl] = y;

            // reduce 32 d-lanes of this row (each 32-lane half-wave = one row)
            float s = lad;
            s += __shfl_xor(s, 1, 64);
            s += __shfl_xor(s, 2, 64);
            s += __shfl_xor(s, 4, 64);
            s += __shfl_xor(s, 8, 64);
            s += __shfl_xor(s, 16, 64);
            if ((lane & 31) == 0) out[(size_t)NROWS * 64 + grow] = s;
        }
    }
}

extern "C" void kernel_launch(void* const* d_in, const int* in_sizes, int n_in,
                              void* d_out, int out_size, void* d_ws, size_t ws_size,
                              hipStream_t stream) {
    const float* inp = (const float*)d_in[0];
    const float* W1  = (const float*)d_in[1];
    const float* b1  = (const float*)d_in[2];
    const float* W2  = (const float*)d_in[3];
    const float* b2  = (const float*)d_in[4];
    float* out = (float*)d_out;
    short* wsp = (short*)d_ws;      // 851968 B: W2F pairs + W1F pairs

    static bool attr_done = false;
    if (!attr_done) {
        hipFuncSetAttribute((const void*)rqs_fused,
                            hipFuncAttributeMaxDynamicSharedMemorySize, LDS_TOTAL);
        attr_done = true;
    }

    hipLaunchKernelGGL(prep_w, dim3(104), dim3(256), 0, stream, W2, W1, wsp);
    hipLaunchKernelGGL(rqs_fused, dim3(NBLOCKS), dim3(NTHREADS), LDS_TOTAL, stream,
                       inp, b1, (const short*)wsp, b2, out);
}

// Round 14
// 255.837 us; speedup vs baseline: 3.9215x; 3.9215x over previous
//
#include <hip/hip_runtime.h>
#include <math.h>

#define NROWS 131072
#define HID 256
#define NPAR 800
#define MROWS 64
#define NTHREADS 1024
#define NBLOCKS (NROWS / MROWS)      // 2048

#define W2F_FRAGS 25600              // 50 col-tiles * 8 k-steps * 64 lanes
#define W1F_BASE  51200              // s16x8 units: after W2F hi/lo pairs
#define LDS_HLO 32768
#define LDS_X   65536
#define LDS_PLD 804                  // 4*804 mod 32 banks = 16 -> quarter-groups 2-way (free)
#define LDS_TOTAL (32 * LDS_PLD * 4) // 102912; p_lds[32][804] overlays hhi/hlo/x

typedef __attribute__((ext_vector_type(8))) short s16x8;
typedef __attribute__((ext_vector_type(4))) float f32x4;

__device__ __forceinline__ unsigned short bf16_rne(float f) {
    unsigned u = __float_as_uint(f);
    u += 0x7fffu + ((u >> 16) & 1u);
    return (unsigned short)(u >> 16);
}
__device__ __forceinline__ float bf16_to_f(unsigned short h) {
    return __uint_as_float((unsigned)h << 16);
}

// Pre-split W2 (fp32 [256][800]) and W1 (fp32 [32][256]) into bf16 hi/lo fragment
// pairs in per-lane MFMA B-operand order (hi/lo PAIRED, 32B contiguous per lane):
//   W2: pair g = ct*8+k0; lane l: 8 bf16 = W2[k0*32+(l>>4)*8+j][ct*16+(l&15)]
//   W1: ct in [0,16); lane l: 8 bf16 = W1[(l>>4)*8+j][ct*16+(l&15)]
__global__ void prep_w(const float* __restrict__ W2, const float* __restrict__ W1,
                       short* __restrict__ wsp)
{
    const int t = blockIdx.x * 256 + threadIdx.x;
    if (t < W2F_FRAGS) {
        const int l = t & 63;
        const int g = t >> 6;
        const int ct = g >> 3, k0 = g & 7;
        const int c  = (ct << 4) + (l & 15);
        const int kb = (k0 << 5) + ((l >> 4) << 3);
        s16x8 hi, lo;
#pragma unroll
        for (int j = 0; j < 8; ++j) {
            float v = W2[(size_t)(kb + j) * NPAR + c];
            unsigned short h = bf16_rne(v);
            unsigned short lw = bf16_rne(v - bf16_to_f(h));
            hi[j] = (short)h;
            lo[j] = (short)lw;
        }
        ((s16x8*)wsp)[g * 128 + l * 2]     = hi;
        ((s16x8*)wsp)[g * 128 + l * 2 + 1] = lo;
    } else if (t < W2F_FRAGS + 1024) {
        const int t1 = t - W2F_FRAGS;
        const int l  = t1 & 63;
        const int ct = t1 >> 6;                 // 0..15
        const int c  = (ct << 4) + (l & 15);
        const int kb = (l >> 4) << 3;
        s16x8 hi, lo;
#pragma unroll
        for (int j = 0; j < 8; ++j) {
            float v = W1[(size_t)(kb + j) * HID + c];
            unsigned short h = bf16_rne(v);
            unsigned short lw = bf16_rne(v - bf16_to_f(h));
            hi[j] = (short)h;
            lo[j] = (short)lw;
        }
        ((s16x8*)wsp)[W1F_BASE + ct * 128 + l * 2]     = hi;
        ((s16x8*)wsp)[W1F_BASE + ct * 128 + l * 2 + 1] = lo;
    }
}

__global__ __launch_bounds__(NTHREADS, 4)
void rqs_fused(const float* __restrict__ inp,
               const float* __restrict__ b1,
               const short* __restrict__ W2F,
               const float* __restrict__ b2,
               float* __restrict__ out)
{
    extern __shared__ char smem[];
    char*  hhi   = smem;                       // [64][256] bf16, XOR-swizzled (32 KB)
    char*  hlo   = smem + LDS_HLO;             // [64][256] bf16, XOR-swizzled (32 KB)
    char*  x_c   = smem + LDS_X;               // [64][32] fp32 x_id, XOR-swizzled (8 KB)
    float* p_lds = (float*)smem;               // [32][804] fp32, overlays (h,x dead by then)

    const int t    = threadIdx.x;
    const int row0 = blockIdx.x * MROWS;
    const int lane = t & 63;
    const int w    = t >> 6;                   // wave id 0..15
    const int arow = lane & 15;
    const int kgrp = lane >> 4;
    const int lane2 = lane << 1;

    const s16x8* BF = (const s16x8*)W2F;

    // wave w owns ct = w + 16*ci; waves 0,1 have 4 tiles (ct up to 49), rest 3.
    const int nct = (w < 2) ? 4 : 3;

    // ---- identity pass-through + x_id -> LDS (swizzled): 64 rows x 8 float4 ----
    if (t < 512) {
        const int r = t >> 3, q = t & 7;
        const float4 v = ((const float4*)(inp + (size_t)(row0 + r) * 64))[q];
        ((float4*)(out + (size_t)(row0 + r) * 64))[q] = v;
        int byte = (r << 7) + (q << 4);
        byte ^= (r & 7) << 4;                                    // bank swizzle
        *(float4*)(x_c + byte) = v;
    }
    __syncthreads();

    // ---- GEMM1 via MFMA: h = relu(x_id @ W1 + b1), 3-term bf16 split ----
    // wave w: row-half (w>>3), col-pair (w&7) -> 2 col-tiles x 2 row-tiles.
    {
        const int rh = w >> 3;                  // row half 0/1 (wave-uniform)
        const int wc = w & 7;                   // col pair 0..7

        s16x8 w1h[2], w1l[2];
#pragma unroll
        for (int cc = 0; cc < 2; ++cc) {
            const int f = (2 * wc + cc) * 128 + W1F_BASE + lane2;
            w1h[cc] = BF[f];
            w1l[cc] = BF[f + 1];
        }

        s16x8 xhi[2], xlo[2];
#pragma unroll
        for (int rt = 0; rt < 2; ++rt) {
            const int row  = rh * 32 + rt * 16 + arow;
            const int base = (row << 7) + (kgrp << 5);
            const int sw   = (row & 7) << 4;
            const float4 va = *(const float4*)(x_c + (base ^ sw));
            const float4 vb = *(const float4*)(x_c + ((base + 16) ^ sw));
            const float xv[8] = {va.x, va.y, va.z, va.w, vb.x, vb.y, vb.z, vb.w};
#pragma unroll
            for (int j = 0; j < 8; ++j) {
                unsigned short h = bf16_rne(xv[j]);
                xhi[rt][j] = (short)h;
                xlo[rt][j] = (short)bf16_rne(xv[j] - bf16_to_f(h));
            }
        }

        f32x4 g[2][2];
#pragma unroll
        for (int cc = 0; cc < 2; ++cc) {
            const float bias = b1[(2 * wc + cc) * 16 + arow];
            g[0][cc] = (f32x4){bias, bias, bias, bias};
            g[1][cc] = (f32x4){bias, bias, bias, bias};
        }

#pragma unroll
        for (int rt = 0; rt < 2; ++rt) {
#pragma unroll
            for (int cc = 0; cc < 2; ++cc) {
                g[rt][cc] = __builtin_amdgcn_mfma_f32_16x16x32_bf16(xhi[rt], w1h[cc], g[rt][cc], 0, 0, 0);
                g[rt][cc] = __builtin_amdgcn_mfma_f32_16x16x32_bf16(xhi[rt], w1l[cc], g[rt][cc], 0, 0, 0);
                g[rt][cc] = __builtin_amdgcn_mfma_f32_16x16x32_bf16(xlo[rt], w1h[cc], g[rt][cc], 0, 0, 0);
            }
        }

        // relu + bf16 hi/lo split + write to hhi/hlo (same layout GEMM2 reads)
#pragma unroll
        for (int rt = 0; rt < 2; ++rt) {
#pragma unroll
            for (int cc = 0; cc < 2; ++cc) {
                const int col = (2 * wc + cc) * 16 + arow;
#pragma unroll
                for (int i = 0; i < 4; ++i) {
                    const int row = rh * 32 + rt * 16 + (kgrp << 2) + i;
                    const float s = fmaxf(g[rt][cc][i], 0.0f);
                    unsigned short hs = bf16_rne(s);
                    unsigned short ls = bf16_rne(s - bf16_to_f(hs));
                    int byte = (row << 9) + (col << 1);
                    byte ^= (row & 7) << 4;
                    *(short*)(hhi + byte) = (short)hs;
                    *(short*)(hlo + byte) = (short)ls;
                }
            }
        }
    }
    __syncthreads();

    // ---- epilogue x prefetch: both phases, hidden under GEMM2 ----
    float x_ep[2];
#pragma unroll
    for (int ph = 0; ph < 2; ++ph)
        x_ep[ph] = inp[(size_t)(row0 + ph * 32 + (t >> 5)) * 64 + 32 + (t & 31)];

    // ---- GEMM2: 3-term bf16 split (hi*hi + hi*lo + lo*hi), acc[4][4] ----
    f32x4 acc[4][4];
#pragma unroll
    for (int ci = 0; ci < 4; ++ci)
#pragma unroll
        for (int rt = 0; rt < 4; ++rt)
            acc[ci][rt] = (f32x4){0.f, 0.f, 0.f, 0.f};

#pragma unroll 1
    for (int k0 = 0; k0 < 8; ++k0) {
        s16x8 ahi[4], alo[4];
#pragma unroll
        for (int rt = 0; rt < 4; ++rt) {
            const int row = rt * 16 + arow;
            int byte = (row << 9) + (k0 << 6) + (kgrp << 4);
            byte ^= (row & 7) << 4;
            ahi[rt] = *(const s16x8*)(hhi + byte);
            alo[rt] = *(const s16x8*)(hlo + byte);
        }
#pragma unroll
        for (int ci = 0; ci < 4; ++ci) {
            if (ci < nct) {
                const int ct = w + (ci << 4);                    // max 49
                const int f  = (ct * 8 + k0) * 128 + lane2;
                const s16x8 bh = BF[f];
                const s16x8 bl = BF[f + 1];
                __builtin_amdgcn_s_setprio(1);
#pragma unroll
                for (int rt = 0; rt < 4; ++rt) {
                    acc[ci][rt] = __builtin_amdgcn_mfma_f32_16x16x32_bf16(ahi[rt], bh, acc[ci][rt], 0, 0, 0);
                    acc[ci][rt] = __builtin_amdgcn_mfma_f32_16x16x32_bf16(ahi[rt], bl, acc[ci][rt], 0, 0, 0);
                    acc[ci][rt] = __builtin_amdgcn_mfma_f32_16x16x32_bf16(alo[rt], bh, acc[ci][rt], 0, 0, 0);
                }
                __builtin_amdgcn_s_setprio(0);
            }
        }
    }

    // ---- epilogue: 2 phases (row halves of 32); stage 32 x 800, then 1024 units ----
#pragma unroll
    for (int rhalf = 0; rhalf < 2; ++rhalf) {
        __syncthreads();                                        // p_lds safe to (re)write
#pragma unroll
        for (int ci = 0; ci < 4; ++ci) {
            if (ci < nct) {
                const int ct = w + (ci << 4);
                const float bias = b2[(ct << 4) + arow];
                const int col = (ct << 4) + arow;               // 0..799
#pragma unroll
                for (int rr = 0; rr < 2; ++rr) {
                    const int rt = rhalf * 2 + rr;
                    const f32x4 v = acc[ci][rt];
                    const int rowl = (rr << 4) + (kgrp << 2);   // 0..31 (+reg)
                    p_lds[(rowl + 0) * LDS_PLD + col] = v[0] + bias;
                    p_lds[(rowl + 1) * LDS_PLD + col] = v[1] + bias;
                    p_lds[(rowl + 2) * LDS_PLD + col] = v[2] + bias;
                    p_lds[(rowl + 3) * LDS_PLD + col] = v[3] + bias;
                }
            }
        }
        __syncthreads();

        // one (row, d) per thread: 32 rows x 32 d = 1024 units
        {
            const int r_l = t >> 5;
            const int dl  = t & 31;
            const float* p = &p_lds[r_l * LDS_PLD + dl * 25];
            float pv[25];
#pragma unroll
            for (int j = 0; j < 25; ++j) pv[j] = p[j];

            float cw[9], ch[9];
            {
                float mw = pv[0];
#pragma unroll
                for (int j = 1; j < 8; ++j) mw = fmaxf(mw, pv[j]);
                float e[8], sw = 0.f;
#pragma unroll
                for (int j = 0; j < 8; ++j) { e[j] = __expf(pv[j] - mw); sw += e[j]; }
                const float scale = 0.992f / sw;
                float run = 0.f;
                cw[0] = 0.f;
#pragma unroll
                for (int j = 0; j < 8; ++j) { run += 0.001f + e[j] * scale; cw[j + 1] = run; }
                const float icn = 1.0f / fmaxf(cw[8], 1e-12f);
#pragma unroll
                for (int j = 1; j <= 8; ++j) cw[j] *= icn;
            }
            {
                float mh = pv[8];
#pragma unroll
                for (int j = 1; j < 8; ++j) mh = fmaxf(mh, pv[8 + j]);
                float e[8], sh = 0.f;
#pragma unroll
                for (int j = 0; j < 8; ++j) { e[j] = __expf(pv[8 + j] - mh); sh += e[j]; }
                const float scale = 0.992f / sh;
                float run = 0.f;
                ch[0] = 0.f;
#pragma unroll
                for (int j = 0; j < 8; ++j) { run += 0.001f + e[j] * scale; ch[j + 1] = run; }
                const float icn = 1.0f / fmaxf(ch[8], 1e-12f);
#pragma unroll
                for (int j = 1; j <= 8; ++j) ch[j] *= icn;
            }

            const int grow = row0 + rhalf * 32 + r_l;
            const float x = x_ep[rhalf];
            const float xs = fminf(fmaxf((x + 10.0f) * 0.05f, 0.f), 1.f);
            int b = 0;
#pragma unroll
            for (int j = 1; j <= 8; ++j) b += (xs >= cw[j]) ? 1 : 0;
            b = min(b, 7);

            float xk = 0.f, wk = 0.f, yk = 0.f, hk = 0.f;
#pragma unroll
            for (int j = 0; j < 8; ++j) {
                if (b == j) {
                    xk = cw[j]; wk = cw[j + 1] - cw[j];
                    yk = ch[j]; hk = ch[j + 1] - ch[j];
                }
            }
            // softplus only on the selected pair d[b], d[b+1]
            float ud0 = pv[16], ud1 = pv[17];
#pragma unroll
            for (int j = 1; j < 8; ++j) {
                const bool ge = (b >= j);
                ud0 = ge ? pv[16 + j] : ud0;
                ud1 = ge ? pv[17 + j] : ud1;
            }
            const float dk  = 0.001f + fmaxf(ud0, 0.f) + __logf(1.0f + __expf(-fabsf(ud0)));
            const float dk1 = 0.001f + fmaxf(ud1, 0.f) + __logf(1.0f + __expf(-fabsf(ud1)));

            const float EPSf = 1e-12f;
            const float tt = fminf(fmaxf((xs - xk) / (wk + EPSf), 0.f), 1.f);
            const float a = (hk + EPSf) / (wk + EPSf);
            const float omt = 1.f - tt;
            const float tomt = tt * omt;
            const float num = a * tt * tt + dk * tomt;
            const float den = a + (dk + dk1 - 2.f * a) * tomt;
            const float sres = num / (den + EPSf);
            const float ys = yk + hk * sres;
            float y = ys * 20.0f - 10.0f;
            const float dnum = a * a * (dk1 * tt * tt + 2.f * a * tomt + dk * omt * omt);
            const float dydx = dnum / (den * den + EPSf);
            float lad = __logf(fmaxf(dydx, 1e-12f));

            const bool inside = (x >= -10.0f) && (x <= 10.0f);
            if (!inside) { y = x; lad = 0.0f; }

            out[(size_t)grow * 64 + 32 + dl] = y;

            // reduce 32 d-lanes of this row (each 32-lane half-wave = one row)
            float s = lad;
            s += __shfl_xor(s, 1, 64);
            s += __shfl_xor(s, 2, 64);
            s += __shfl_xor(s, 4, 64);
            s += __shfl_xor(s, 8, 64);
            s += __shfl_xor(s, 16, 64);
            if ((lane & 31) == 0) out[(size_t)NROWS * 64 + grow] = s;
        }
    }
}

extern "C" void kernel_launch(void* const* d_in, const int* in_sizes, int n_in,
                              void* d_out, int out_size, void* d_ws, size_t ws_size,
                              hipStream_t stream) {
    const float* inp = (const float*)d_in[0];
    const float* W1  = (const float*)d_in[1];
    const float* b1  = (const float*)d_in[2];
    const float* W2  = (const float*)d_in[3];
    const float* b2  = (const float*)d_in[4];
    float* out = (float*)d_out;
    short* wsp = (short*)d_ws;      // 851968 B: W2F pairs + W1F pairs

    static bool attr_done = false;
    if (!attr_done) {
        hipFuncSetAttribute((const void*)rqs_fused,
                            hipFuncAttributeMaxDynamicSharedMemorySize, LDS_TOTAL);
        attr_done = true;
    }

    hipLaunchKernelGGL(prep_w, dim3(104), dim3(256), 0, stream, W2, W1, wsp);
    hipLaunchKernelGGL(rqs_fused, dim3(NBLOCKS), dim3(NTHREADS), LDS_TOTAL, stream,
                       inp, b1, (const short*)wsp, b2, out);
}